// Round 6
// baseline (278.621 us; speedup 1.0000x reference)
//
#include <hip/hip_runtime.h>
#include <math.h>

typedef __attribute__((ext_vector_type(8))) short bf16x8;
typedef __attribute__((ext_vector_type(16))) float f32x16;

#define Bsz 4
#define Nn 1024
#define TN 3072
#define Dd 256
#define Hh 4
#define DH 64
#define TAUc 1e-3f
#define QSCALE 0.1803368801111f   // log2(e)/8 : softmax done in exp2 domain

// workspace layout (float offsets)
#define SALP_OFF 0           // 98304 (4 b x 96 slabs x 256 d partial sums)
#define IDX_OFF  98304       // 256 ints
#define XCB_OFF  98560       // bf16 (4,3072,64) = 393216 floats
#define WCT_OFF  491776      // bf16 (4,3,256,64) = 98304 floats
#define QB_OFF   590080      // bf16 (16,3072,64) = 1572864 floats
#define KB_OFF   2162944     // bf16 (16,3072,64)
#define VT_OFF   3735808     // bf16 (16,64,3072), key idx bit2<->bit3 swapped
#define OP0_OFF  5308672     // fp32 (4,3072,256) split-K partial 0
#define OP1_OFF  8454400     // fp32 partial 1
#define SML_OFF  11600128    // float [2][16][3072] row sums l

__device__ __forceinline__ ushort f2b(float f) {
    uint u = __float_as_uint(f);
    u += 0x7fffu + ((u >> 16) & 1u);
    return (ushort)(u >> 16);
}
__device__ __forceinline__ uint pk2(float a, float b) {   // RNE pack (software)
    return (uint)f2b(a) | ((uint)f2b(b) << 16);
}
__device__ __forceinline__ uint trunc_pk(float a, float b) {
    return (__float_as_uint(a) >> 16) | (__float_as_uint(b) & 0xFFFF0000u);
}
__device__ __forceinline__ float hi_f(float a) {
    return __uint_as_float(__float_as_uint(a) & 0xFFFF0000u);
}
__device__ __forceinline__ uint cvtpk(float a, float b) {  // HW RNE pack
    uint r;
    asm("v_cvt_pk_bf16_f32 %0, %1, %2" : "=v"(r) : "v"(a), "v"(b));
    return r;
}
union U4B8 { uint u[4]; bf16x8 v; };
__device__ __forceinline__ bf16x8 ld8(const ushort* p) { return *(const bf16x8*)p; }

// ---- kernel 1: per-channel saliency partial sums ----
__global__ __launch_bounds__(256) void k_sal(
        const float* __restrict__ F0, const float* __restrict__ F1,
        const float* __restrict__ F2, float* __restrict__ salp) {
    int b = blockIdx.x / 96;
    int slab = blockIdx.x - b * 96;
    int t0 = slab * 32;
    int seg = t0 >> 10, tt0 = t0 & 1023;
    const float* F = (seg == 0) ? F0 : (seg == 1 ? F1 : F2);
    const float* base = &F[(size_t)((b << 10) + tt0) * Dd + threadIdx.x];
    float acc = 0.f;
    #pragma unroll 4
    for (int r = 0; r < 32; ++r) {
        float x = base[(size_t)r * Dd];
        acc += fmaxf(fabsf(x) - TAUc, 0.f);
    }
    salp[blockIdx.x * 256 + threadIdx.x] = acc;
}

// ---- kernel 2: reduce partials + top-64 selection (bitonic sort 256) ----
__global__ void k_topk(const float* __restrict__ salp, int* __restrict__ idx) {
    __shared__ float v[256];
    __shared__ int cnt;
    int b = blockIdx.x, tid = threadIdx.x;
    float myval = 0.f;
    const float* p = &salp[(size_t)b * 96 * 256 + tid];
    #pragma unroll 4
    for (int s = 0; s < 96; ++s) myval += p[s * 256];
    v[tid] = myval;
    if (tid == 0) cnt = 0;
    __syncthreads();
    for (int k = 2; k <= 256; k <<= 1)
        for (int j = k >> 1; j > 0; j >>= 1) {
            int ixj = tid ^ j;
            if (ixj > tid) {
                float a = v[tid], c = v[ixj];
                bool up = ((tid & k) == 0);
                if ((a > c) == up) { v[tid] = c; v[ixj] = a; }
            }
            __syncthreads();
        }
    float thr = v[192];
    if (myval >= thr) {
        int p2 = atomicAdd(&cnt, 1);
        if (p2 < 64) idx[b * 64 + p2] = tid;
    }
}

// ---- kernel 3: merged gathers (blocks 0..383: X; 384..767: W columns) ----
__global__ __launch_bounds__(256) void k_gather(
        const float* __restrict__ F0, const float* __restrict__ F1,
        const float* __restrict__ F2,
        const float* __restrict__ Wq, const float* __restrict__ Wk,
        const float* __restrict__ Wv, const int* __restrict__ idx,
        uint* __restrict__ Xcb, uint* __restrict__ Wct) {
    __shared__ float xs[32 * 260];
    __shared__ int ids[64];
    int tid = threadIdx.x;
    if (blockIdx.x < 384) {
        int b = blockIdx.x / 96;
        int t0 = (blockIdx.x - b * 96) * 32;
        if (tid < 64) ids[tid] = idx[b * 64 + tid];
        int seg = t0 >> 10, tt0 = t0 & 1023;
        const float* F = (seg == 0) ? F0 : (seg == 1 ? F1 : F2);
        const float* base = &F[(size_t)((b << 10) + tt0) * Dd];
        #pragma unroll
        for (int i = 0; i < 8; ++i) {
            int i0 = tid + i * 256;
            int r = i0 >> 6, c4 = (i0 & 63) << 2;
            float4 x = *(const float4*)&base[(size_t)r * Dd + c4];
            x.x = copysignf(fmaxf(fabsf(x.x) - TAUc, 0.f), x.x);
            x.y = copysignf(fmaxf(fabsf(x.y) - TAUc, 0.f), x.y);
            x.z = copysignf(fmaxf(fabsf(x.z) - TAUc, 0.f), x.z);
            x.w = copysignf(fmaxf(fabsf(x.w) - TAUc, 0.f), x.w);
            *(float4*)&xs[r * 260 + c4] = x;
        }
        __syncthreads();
        #pragma unroll
        for (int i = 0; i < 4; ++i) {
            int i0 = tid + i * 256;
            int r = i0 >> 5, jp = i0 & 31;
            float x0 = xs[r * 260 + ids[2 * jp]];
            float x1 = xs[r * 260 + ids[2 * jp + 1]];
            Xcb[(size_t)(b * TN + t0 + r) * 32 + jp] = pk2(x0, x1);
        }
    } else {
        int gid = (blockIdx.x - 384) * 256 + tid;   // 98304
        int b = gid / 24576;
        if (tid < 64) ids[tid] = idx[b * 64 + tid];
        __syncthreads();
        int rem = gid - b * 24576;
        int mat = rem / 8192;
        int rem2 = rem - mat * 8192;
        int dout = rem2 >> 5, jp = rem2 & 31;
        const float* Wm = (mat == 0) ? Wq : (mat == 1 ? Wk : Wv);
        float w0 = Wm[(size_t)dout * 256 + ids[2 * jp]];
        float w1 = Wm[(size_t)dout * 256 + ids[2 * jp + 1]];
        Wct[((size_t)(b * 3 + mat) * 256 + dout) * 32 + jp] = pk2(w0, w1);
    }
}

// ---- kernel 4: QKV projection, 32x32x16 MFMA, LDS-free, COALESCED stores ----
// Q/K: D = X*W^T (m=t rows, n=dout lanes -> d-contiguous ushort stores)
// V:   D = W*X^T (m=dout rows, n=t lanes -> t-contiguous stores, swap23 on lane)
__global__ __launch_bounds__(256) void k_qkv(
        const ushort* __restrict__ Xcb, const ushort* __restrict__ Wct,
        const float* __restrict__ bq, const float* __restrict__ bk,
        const float* __restrict__ bv,
        ushort* __restrict__ Qh, ushort* __restrict__ Kh, ushort* __restrict__ Vt) {
    int wave = threadIdx.x >> 6, lane = threadIdx.x & 63;
    int l31 = lane & 31, h = lane >> 5;
    int W = blockIdx.x * 4 + wave;          // 2304 wave-tasks
    int b = W / 576;
    int r = W - b * 576;
    int mat = r / 192;
    int p = r - mat * 192;
    const ushort* Xb = Xcb + (size_t)b * TN * 64;
    const ushort* Wm = Wct + (size_t)(b * 3 + mat) * 256 * 64;
    f32x16 c[4];
    #pragma unroll
    for (int nt = 0; nt < 4; ++nt)
        #pragma unroll
        for (int q = 0; q < 16; ++q) c[nt][q] = 0.f;
    if (mat < 2) {
        int mtt = p % 96, ng = p / 96;      // t tile, dout half
        const ushort* arow = &Xb[(size_t)(mtt * 32 + l31) * 64];
        #pragma unroll
        for (int kc = 0; kc < 4; ++kc) {
            bf16x8 af = ld8(arow + kc * 16 + 8 * h);
            #pragma unroll
            for (int nt = 0; nt < 4; ++nt) {
                bf16x8 bf = ld8(&Wm[(size_t)(ng * 128 + nt * 32 + l31) * 64 + kc * 16 + 8 * h]);
                c[nt] = __builtin_amdgcn_mfma_f32_32x32x16_bf16(af, bf, c[nt], 0, 0, 0);
            }
        }
        const float* bias = mat ? bk : bq;
        float sc = mat ? 1.0f : QSCALE;
        ushort* Out = mat ? Kh : Qh;
        #pragma unroll
        for (int nt = 0; nt < 4; ++nt) {
            int dout = ng * 128 + nt * 32 + l31;
            int head = dout >> 6, d63 = dout & 63;
            float bb = bias[dout];
            size_t obase = ((size_t)(b * 4 + head) * TN + mtt * 32) * 64 + d63;
            #pragma unroll
            for (int u = 0; u < 16; ++u) {
                int trow = (u & 3) + 8 * (u >> 2) + 4 * h;
                Out[obase + (size_t)trow * 64] = f2b((c[nt][u] + bb) * sc);
            }
        }
    } else {
        int mtv = p & 7, tg = p >> 3;       // dout tile (8), t group (24)
        const ushort* arow = &Wm[(size_t)(mtv * 32 + l31) * 64];
        #pragma unroll
        for (int kc = 0; kc < 4; ++kc) {
            bf16x8 af = ld8(arow + kc * 16 + 8 * h);
            #pragma unroll
            for (int nt = 0; nt < 4; ++nt) {
                bf16x8 bf = ld8(&Xb[(size_t)(tg * 128 + nt * 32 + l31) * 64 + kc * 16 + 8 * h]);
                c[nt] = __builtin_amdgcn_mfma_f32_32x32x16_bf16(af, bf, c[nt], 0, 0, 0);
            }
        }
        int head = mtv >> 1;
        int sl = (l31 & 19) | ((l31 & 4) << 1) | ((l31 & 8) >> 1);  // swap bits 2<->3
        #pragma unroll
        for (int nt = 0; nt < 4; ++nt) {
            size_t tslot = (size_t)(tg * 128 + nt * 32 + sl);
            #pragma unroll
            for (int u = 0; u < 16; ++u) {
                int dout = mtv * 32 + (u & 3) + 8 * (u >> 2) + 4 * h;
                int d63 = dout & 63;
                Vt[((size_t)(b * 4 + head) * 64 + d63) * TN + tslot] =
                    f2b(c[nt][u] + bv[dout]);
            }
        }
    }
}

// ---- kernel 5: flash attention, BK=128, wave-level 64q x 64key split ----
// K/V frags reused across 2 q-tiles -> 16 LDS reads/wave/stage (was 32).
// P stays in registers (r5-verified mapping, wk-local). In-block combine of
// the two key-half waves via the 32KB staging LDS (valid: no online max).
__global__ __launch_bounds__(256, 3) void k_attn(
        const ushort* __restrict__ Qg, const ushort* __restrict__ Kg,
        const ushort* __restrict__ Vtg,
        float* __restrict__ OP0, float* __restrict__ OP1,
        float* __restrict__ Sml) {
    __shared__ __align__(16) ushort SM[128 * 64 + 64 * 128];  // Ks | Vts
    __shared__ float lsh[128];
    ushort* Ks = SM;
    ushort* Vts = SM + 128 * 64;
    int bh = blockIdx.x / 48;
    int rem = blockIdx.x - bh * 48;
    int qt = rem >> 1, ks = rem & 1;
    int b = bh >> 2, hh = bh & 3;
    int tid = threadIdx.x, wave = tid >> 6, lane = tid & 63;
    int l31 = lane & 31, h = lane >> 5;
    int wq = wave & 1, wk = wave >> 1;
    int q0 = qt * 128 + wq * 64;
    const ushort* Qb = Qg + ((size_t)bh * TN + q0) * DH;
    bf16x8 qf[2][4];
    #pragma unroll
    for (int nq = 0; nq < 2; ++nq)
        #pragma unroll
        for (int kc = 0; kc < 4; ++kc)
            qf[nq][kc] = ld8(&Qb[(size_t)(nq * 32 + l31) * DH + kc * 16 + 8 * h]);

    // staging addresses (thread-fixed, all 4 waves cooperate)
    int krow0 = tid >> 3, kcc = tid & 7;
    int vrow0 = tid >> 4, vch = tid & 15;
    int kt0 = ks * 1536;
    const ushort* KbL = Kg + (size_t)bh * TN * DH + (size_t)(kt0 + krow0) * 64 + kcc * 8;
    const ushort* VtL = Vtg + (size_t)bh * DH * TN + (size_t)vrow0 * TN + kt0 + vch * 8;

    f32x16 o[2][2];   // [mq][nd]
    #pragma unroll
    for (int mq = 0; mq < 2; ++mq)
        #pragma unroll
        for (int nd = 0; nd < 2; ++nd)
            #pragma unroll
            for (int q = 0; q < 16; ++q) o[mq][nd][q] = 0.f;
    float lrun[2] = {0.f, 0.f};

    int fq0 = (l31 ^ (l31 >> 3)) & 7;
    int fq1 = ((32 + l31) ^ ((32 + l31) >> 3)) & 7;

    #pragma unroll 1
    for (int it = 0; it < 12; ++it) {
        __syncthreads();
        #pragma unroll
        for (int i = 0; i < 4; ++i) {
            int kr = krow0 + 32 * i;
            int fk = (kr ^ (kr >> 3)) & 7;
            *(uint4*)&Ks[kr * 64 + ((kcc ^ fk) << 3)] =
                *(const uint4*)(KbL + (size_t)(32 * i) * 64);
            int vr = vrow0 + 16 * i;
            int fv = (vr ^ (vr >> 3)) & 7;
            *(uint4*)&Vts[vr * 128 + (((vch & 8) | ((vch & 7) ^ fv)) << 3)] =
                *(const uint4*)(VtL + (size_t)(16 * i) * TN);
        }
        KbL += 128 * 64;
        VtL += 128;
        __syncthreads();

        #pragma unroll
        for (int mk = 0; mk < 2; ++mk) {
            int rowk = wk * 64 + mk * 32 + l31;
            int fk = (rowk ^ (rowk >> 3)) & 7;
            bf16x8 kf[4];
            #pragma unroll
            for (int kc = 0; kc < 4; ++kc)
                kf[kc] = ld8(&Ks[rowk * 64 + (((2 * kc + h) ^ fk) << 3)]);
            uint pkk[2][8];
            #pragma unroll
            for (int mq = 0; mq < 2; ++mq) {
                f32x16 s;
                #pragma unroll
                for (int q = 0; q < 16; ++q) s[q] = 0.f;
                #pragma unroll
                for (int kc = 0; kc < 4; ++kc)
                    s = __builtin_amdgcn_mfma_f32_32x32x16_bf16(kf[kc], qf[mq][kc], s, 0, 0, 0);
                #pragma unroll
                for (int u = 0; u < 8; ++u) {
                    float pa = exp2f(s[2 * u]), pb = exp2f(s[2 * u + 1]);
                    lrun[mq] += pa + pb;
                    pkk[mq][u] = cvtpk(pa, pb);
                }
            }
            // PV for this mk's two 16-key chunks; V-frags reused across mq
            #pragma unroll
            for (int c2 = 0; c2 < 2; ++c2) {
                int ch = 8 * wk + 4 * mk + 2 * c2 + h;
                bf16x8 v0f = ld8(&Vts[l31 * 128 + (((ch & 8) | ((ch & 7) ^ fq0)) << 3)]);
                bf16x8 v1f = ld8(&Vts[(32 + l31) * 128 + (((ch & 8) | ((ch & 7) ^ fq1)) << 3)]);
                #pragma unroll
                for (int mq = 0; mq < 2; ++mq) {
                    U4B8 pf;
                    pf.u[0] = pkk[mq][4 * c2];     pf.u[1] = pkk[mq][4 * c2 + 1];
                    pf.u[2] = pkk[mq][4 * c2 + 2]; pf.u[3] = pkk[mq][4 * c2 + 3];
                    o[mq][0] = __builtin_amdgcn_mfma_f32_32x32x16_bf16(pf.v, v0f, o[mq][0], 0, 0, 0);
                    o[mq][1] = __builtin_amdgcn_mfma_f32_32x32x16_bf16(pf.v, v1f, o[mq][1], 0, 0, 0);
                }
            }
        }
    }

    // fold the h-halves of l (k-dim split inside QK fragments)
    #pragma unroll
    for (int mq = 0; mq < 2; ++mq) lrun[mq] += __shfl_xor(lrun[mq], 32);

    // in-block combine of the two key-half waves through LDS
    __syncthreads();
    float* Osh = (float*)SM;   // 128 q x 64 d fp32 = 32 KB
    if (wk == 1) {
        #pragma unroll
        for (int mq = 0; mq < 2; ++mq) {
            #pragma unroll
            for (int u = 0; u < 16; ++u) {
                int qrow = wq * 64 + mq * 32 + (u & 3) + 8 * (u >> 2) + 4 * h;
                Osh[qrow * 64 + l31] = o[mq][0][u];
                Osh[qrow * 64 + 32 + l31] = o[mq][1][u];
            }
            if (h == 0) lsh[wq * 64 + mq * 32 + l31] = lrun[mq];
        }
    }
    __syncthreads();
    if (wk == 0) {
        float* OP = ks ? OP1 : OP0;
        #pragma unroll
        for (int mq = 0; mq < 2; ++mq) {
            #pragma unroll
            for (int u = 0; u < 16; ++u) {
                int qrow = wq * 64 + mq * 32 + (u & 3) + 8 * (u >> 2) + 4 * h;
                float a0 = o[mq][0][u] + Osh[qrow * 64 + l31];
                float a1 = o[mq][1][u] + Osh[qrow * 64 + 32 + l31];
                int t = qt * 128 + qrow;
                size_t base = ((size_t)b * TN + t) * Dd + hh * 64;
                OP[base + l31] = a0;
                OP[base + 32 + l31] = a1;
            }
            if (h == 0) {
                float lt = lrun[mq] + lsh[wq * 64 + mq * 32 + l31];
                Sml[(size_t)ks * 49152 + (size_t)bh * TN + q0 + mq * 32 + l31] = lt;
            }
        }
    }
}

// ---- kernel 6: output projection, LDS-staged, split-bf16 MFMA, fused combine ----
// D = M * Wo^T (m=t rows, n=dout lanes -> d-contiguous stores). M staged per
// 16-din chunk through LDS with coalesced fp32 loads of OP0/OP1.
__global__ __launch_bounds__(256) void k_out(
        const float* __restrict__ OP0, const float* __restrict__ OP1,
        const float* __restrict__ Sml, const float* __restrict__ Wo,
        const float* __restrict__ bo, float* __restrict__ out) {
    __shared__ __align__(16) ushort Mhi[64 * 16];
    __shared__ __align__(16) ushort Mlo[64 * 16];
    __shared__ float invsh[64 * 4];
    int nd4 = blockIdx.x;              // 64-dout group (4)
    int R0 = blockIdx.y * 64;          // 64-token group (192)
    int b = R0 / TN;
    int tloc0 = R0 - b * TN;
    int tid = threadIdx.x, wave = tid >> 6, lane = tid & 63;
    int l31 = lane & 31, h = lane >> 5;
    int wt = wave & 1, wd = wave >> 1;
    // per-token per-head combine scales
    {
        int hd = tid >> 6, t = tid & 63;
        size_t o = (size_t)(b * 4 + hd) * TN + tloc0 + t;
        invsh[t * 4 + hd] = 1.f / (Sml[o] + Sml[49152 + o]);
    }
    int dout = nd4 * 64 + wd * 32 + l31;
    float bb = bo[dout];
    const float* wrow = &Wo[(size_t)dout * 256];
    int st_t = tid >> 2, st_c = tid & 3;
    size_t st_base = ((size_t)(b * TN + tloc0 + st_t)) * 256 + st_c * 4;
    f32x16 acc;
    #pragma unroll
    for (int q = 0; q < 16; ++q) acc[q] = 0.f;
    #pragma unroll 1
    for (int st = 0; st < 16; ++st) {
        __syncthreads();
        int hd = st >> 2;
        {
            size_t ob = st_base + st * 16;
            float4 x = *(const float4*)&OP0[ob];
            float4 y = *(const float4*)&OP1[ob];
            float s = invsh[st_t * 4 + hd];
            float m0 = (x.x + y.x) * s, m1 = (x.y + y.y) * s;
            float m2 = (x.z + y.z) * s, m3 = (x.w + y.w) * s;
            uint2 wh = { trunc_pk(m0, m1), trunc_pk(m2, m3) };
            uint2 wl = { trunc_pk(m0 - hi_f(m0), m1 - hi_f(m1)),
                         trunc_pk(m2 - hi_f(m2), m3 - hi_f(m3)) };
            *(uint2*)&Mhi[st_t * 16 + st_c * 4] = wh;
            *(uint2*)&Mlo[st_t * 16 + st_c * 4] = wl;
        }
        __syncthreads();
        // B-frags from Wo (global, L1-resident across stages)
        int din0 = st * 16 + 8 * h;
        float4 w0 = *(const float4*)&wrow[din0];
        float4 w1 = *(const float4*)&wrow[din0 + 4];
        U4B8 wh, wl;
        wh.u[0] = trunc_pk(w0.x, w0.y); wh.u[1] = trunc_pk(w0.z, w0.w);
        wh.u[2] = trunc_pk(w1.x, w1.y); wh.u[3] = trunc_pk(w1.z, w1.w);
        wl.u[0] = trunc_pk(w0.x - hi_f(w0.x), w0.y - hi_f(w0.y));
        wl.u[1] = trunc_pk(w0.z - hi_f(w0.z), w0.w - hi_f(w0.w));
        wl.u[2] = trunc_pk(w1.x - hi_f(w1.x), w1.y - hi_f(w1.y));
        wl.u[3] = trunc_pk(w1.z - hi_f(w1.z), w1.w - hi_f(w1.w));
        // A-frags from LDS (dense contiguous)
        int trow = wt * 32 + l31;
        bf16x8 ah = *(const bf16x8*)&Mhi[trow * 16 + 8 * h];
        bf16x8 al = *(const bf16x8*)&Mlo[trow * 16 + 8 * h];
        acc = __builtin_amdgcn_mfma_f32_32x32x16_bf16(ah, wh.v, acc, 0, 0, 0);
        acc = __builtin_amdgcn_mfma_f32_32x32x16_bf16(al, wh.v, acc, 0, 0, 0);
        acc = __builtin_amdgcn_mfma_f32_32x32x16_bf16(ah, wl.v, acc, 0, 0, 0);
    }
    #pragma unroll
    for (int u = 0; u < 16; ++u) {
        int tloc = tloc0 + wt * 32 + (u & 3) + 8 * (u >> 2) + 4 * h;
        int chunk = tloc >> 10, tt = tloc & 1023;
        out[(size_t)chunk * (Bsz * Nn * Dd) + ((size_t)(b * Nn + tt)) * Dd + dout] =
            acc[u] + bb;
    }
}

extern "C" void kernel_launch(void* const* d_in, const int* in_sizes, int n_in,
                              void* d_out, int out_size, void* d_ws, size_t ws_size,
                              hipStream_t stream) {
    const float* F0 = (const float*)d_in[0];
    const float* F1 = (const float*)d_in[1];
    const float* F2 = (const float*)d_in[2];
    const float* Wq = (const float*)d_in[3];
    const float* bq = (const float*)d_in[4];
    const float* Wk = (const float*)d_in[5];
    const float* bk = (const float*)d_in[6];
    const float* Wv = (const float*)d_in[7];
    const float* bv = (const float*)d_in[8];
    const float* Wo = (const float*)d_in[9];
    const float* bo = (const float*)d_in[10];
    float* ws = (float*)d_ws;
    float* out = (float*)d_out;

    int* idxp = (int*)(ws + IDX_OFF);
    uint* Xcb = (uint*)(ws + XCB_OFF);
    uint* Wct = (uint*)(ws + WCT_OFF);
    ushort* Qb16 = (ushort*)(ws + QB_OFF);
    ushort* Kb16 = (ushort*)(ws + KB_OFF);
    ushort* Vt16 = (ushort*)(ws + VT_OFF);
    float* OP0 = ws + OP0_OFF;
    float* OP1 = ws + OP1_OFF;
    float* Sml = ws + SML_OFF;

    k_sal<<<384, 256, 0, stream>>>(F0, F1, F2, ws + SALP_OFF);
    k_topk<<<Bsz, 256, 0, stream>>>(ws + SALP_OFF, idxp);
    k_gather<<<768, 256, 0, stream>>>(F0, F1, F2, Wq, Wk, Wv, idxp, Xcb, Wct);
    k_qkv<<<576, 256, 0, stream>>>((const ushort*)Xcb, (const ushort*)Wct,
                                   bq, bk, bv, Qb16, Kb16, Vt16);
    k_attn<<<768, 256, 0, stream>>>(Qb16, Kb16, Vt16, OP0, OP1, Sml);
    k_out<<<dim3(4, 192), 256, 0, stream>>>(OP0, OP1, Sml, Wo, bo, out);
}

// Round 8
// 194.159 us; speedup vs baseline: 1.4350x; 1.4350x over previous
//
#include <hip/hip_runtime.h>
#include <math.h>

typedef __attribute__((ext_vector_type(8))) short bf16x8;
typedef __attribute__((ext_vector_type(16))) float f32x16;

#define Bsz 4
#define Nn 1024
#define TN 3072
#define Dd 256
#define Hh 4
#define DH 64
#define TAUc 1e-3f
#define QSCALE 0.1803368801111f   // log2(e)/8 : softmax done in exp2 domain

// workspace layout (float offsets)
#define SALP_OFF 0           // 98304 (4 b x 96 slabs x 256 d partial sums)
#define IDX_OFF  98304       // 256 ints
#define XCB_OFF  98560       // bf16 (4,3072,64) = 393216 floats
#define WCT_OFF  491776      // bf16 (4,3,256,64) = 98304 floats
#define QB_OFF   590080      // bf16 (16,3072,64) = 1572864 floats
#define KB_OFF   2162944     // bf16 (16,3072,64)
#define VT_OFF   3735808     // bf16 (16,64,3072), key idx bit2<->bit3 swapped
#define OP0_OFF  5308672     // fp32 (4,3072,256) split-K partial 0
#define OP1_OFF  8454400     // fp32 partial 1
#define SML_OFF  11600128    // float [2][16][3072] row sums l

__device__ __forceinline__ ushort f2b(float f) {
    uint u = __float_as_uint(f);
    u += 0x7fffu + ((u >> 16) & 1u);
    return (ushort)(u >> 16);
}
__device__ __forceinline__ uint pk2(float a, float b) {   // RNE pack (software)
    return (uint)f2b(a) | ((uint)f2b(b) << 16);
}
__device__ __forceinline__ uint trunc_pk(float a, float b) {
    return (__float_as_uint(a) >> 16) | (__float_as_uint(b) & 0xFFFF0000u);
}
__device__ __forceinline__ float hi_f(float a) {
    return __uint_as_float(__float_as_uint(a) & 0xFFFF0000u);
}
__device__ __forceinline__ uint cvtpk(float a, float b) {  // HW RNE pack
    uint r;
    asm("v_cvt_pk_bf16_f32 %0, %1, %2" : "=v"(r) : "v"(a), "v"(b));
    return r;
}
union U4B8 { uint u[4]; bf16x8 v; };
__device__ __forceinline__ bf16x8 ld8(const ushort* p) { return *(const bf16x8*)p; }

// ---- kernel 1: per-channel saliency partial sums ----
__global__ __launch_bounds__(256) void k_sal(
        const float* __restrict__ F0, const float* __restrict__ F1,
        const float* __restrict__ F2, float* __restrict__ salp) {
    int b = blockIdx.x / 96;
    int slab = blockIdx.x - b * 96;
    int t0 = slab * 32;
    int seg = t0 >> 10, tt0 = t0 & 1023;
    const float* F = (seg == 0) ? F0 : (seg == 1 ? F1 : F2);
    const float* base = &F[(size_t)((b << 10) + tt0) * Dd + threadIdx.x];
    float acc = 0.f;
    #pragma unroll 4
    for (int r = 0; r < 32; ++r) {
        float x = base[(size_t)r * Dd];
        acc += fmaxf(fabsf(x) - TAUc, 0.f);
    }
    salp[blockIdx.x * 256 + threadIdx.x] = acc;
}

// ---- kernel 2: reduce partials + top-64 selection (bitonic sort 256) ----
__global__ void k_topk(const float* __restrict__ salp, int* __restrict__ idx) {
    __shared__ float v[256];
    __shared__ int cnt;
    int b = blockIdx.x, tid = threadIdx.x;
    float myval = 0.f;
    const float* p = &salp[(size_t)b * 96 * 256 + tid];
    #pragma unroll 4
    for (int s = 0; s < 96; ++s) myval += p[s * 256];
    v[tid] = myval;
    if (tid == 0) cnt = 0;
    __syncthreads();
    for (int k = 2; k <= 256; k <<= 1)
        for (int j = k >> 1; j > 0; j >>= 1) {
            int ixj = tid ^ j;
            if (ixj > tid) {
                float a = v[tid], c = v[ixj];
                bool up = ((tid & k) == 0);
                if ((a > c) == up) { v[tid] = c; v[ixj] = a; }
            }
            __syncthreads();
        }
    float thr = v[192];
    if (myval >= thr) {
        int p2 = atomicAdd(&cnt, 1);
        if (p2 < 64) idx[b * 64 + p2] = tid;
    }
}

// ---- kernel 3: merged gathers (blocks 0..383: X; 384..767: W columns) ----
__global__ __launch_bounds__(256) void k_gather(
        const float* __restrict__ F0, const float* __restrict__ F1,
        const float* __restrict__ F2,
        const float* __restrict__ Wq, const float* __restrict__ Wk,
        const float* __restrict__ Wv, const int* __restrict__ idx,
        uint* __restrict__ Xcb, uint* __restrict__ Wct) {
    __shared__ float xs[32 * 260];
    __shared__ int ids[64];
    int tid = threadIdx.x;
    if (blockIdx.x < 384) {
        int b = blockIdx.x / 96;
        int t0 = (blockIdx.x - b * 96) * 32;
        if (tid < 64) ids[tid] = idx[b * 64 + tid];
        int seg = t0 >> 10, tt0 = t0 & 1023;
        const float* F = (seg == 0) ? F0 : (seg == 1 ? F1 : F2);
        const float* base = &F[(size_t)((b << 10) + tt0) * Dd];
        #pragma unroll
        for (int i = 0; i < 8; ++i) {
            int i0 = tid + i * 256;
            int r = i0 >> 6, c4 = (i0 & 63) << 2;
            float4 x = *(const float4*)&base[(size_t)r * Dd + c4];
            x.x = copysignf(fmaxf(fabsf(x.x) - TAUc, 0.f), x.x);
            x.y = copysignf(fmaxf(fabsf(x.y) - TAUc, 0.f), x.y);
            x.z = copysignf(fmaxf(fabsf(x.z) - TAUc, 0.f), x.z);
            x.w = copysignf(fmaxf(fabsf(x.w) - TAUc, 0.f), x.w);
            *(float4*)&xs[r * 260 + c4] = x;
        }
        __syncthreads();
        #pragma unroll
        for (int i = 0; i < 4; ++i) {
            int i0 = tid + i * 256;
            int r = i0 >> 5, jp = i0 & 31;
            float x0 = xs[r * 260 + ids[2 * jp]];
            float x1 = xs[r * 260 + ids[2 * jp + 1]];
            Xcb[(size_t)(b * TN + t0 + r) * 32 + jp] = pk2(x0, x1);
        }
    } else {
        int gid = (blockIdx.x - 384) * 256 + tid;   // 98304
        int b = gid / 24576;
        if (tid < 64) ids[tid] = idx[b * 64 + tid];
        __syncthreads();
        int rem = gid - b * 24576;
        int mat = rem / 8192;
        int rem2 = rem - mat * 8192;
        int dout = rem2 >> 5, jp = rem2 & 31;
        const float* Wm = (mat == 0) ? Wq : (mat == 1 ? Wk : Wv);
        float w0 = Wm[(size_t)dout * 256 + ids[2 * jp]];
        float w1 = Wm[(size_t)dout * 256 + ids[2 * jp + 1]];
        Wct[((size_t)(b * 3 + mat) * 256 + dout) * 32 + jp] = pk2(w0, w1);
    }
}

// ---- kernel 4: QKV projection, 32x32x16 MFMA, LDS-free, coalesced stores ----
// Q/K: D = X*W^T (m=t rows, n=dout lanes -> d-contiguous ushort stores)
// V:   D = W*X^T (m=dout rows, n=t lanes -> t-contiguous stores, swap23 on lane)
__global__ __launch_bounds__(256) void k_qkv(
        const ushort* __restrict__ Xcb, const ushort* __restrict__ Wct,
        const float* __restrict__ bq, const float* __restrict__ bk,
        const float* __restrict__ bv,
        ushort* __restrict__ Qh, ushort* __restrict__ Kh, ushort* __restrict__ Vt) {
    int wave = threadIdx.x >> 6, lane = threadIdx.x & 63;
    int l31 = lane & 31, h = lane >> 5;
    int W = blockIdx.x * 4 + wave;          // 2304 wave-tasks
    int b = W / 576;
    int r = W - b * 576;
    int mat = r / 192;
    int p = r - mat * 192;
    const ushort* Xb = Xcb + (size_t)b * TN * 64;
    const ushort* Wm = Wct + (size_t)(b * 3 + mat) * 256 * 64;
    f32x16 c[4];
    #pragma unroll
    for (int nt = 0; nt < 4; ++nt)
        #pragma unroll
        for (int q = 0; q < 16; ++q) c[nt][q] = 0.f;
    if (mat < 2) {
        int mtt = p % 96, ng = p / 96;      // t tile, dout half
        const ushort* arow = &Xb[(size_t)(mtt * 32 + l31) * 64];
        #pragma unroll
        for (int kc = 0; kc < 4; ++kc) {
            bf16x8 af = ld8(arow + kc * 16 + 8 * h);
            #pragma unroll
            for (int nt = 0; nt < 4; ++nt) {
                bf16x8 bf = ld8(&Wm[(size_t)(ng * 128 + nt * 32 + l31) * 64 + kc * 16 + 8 * h]);
                c[nt] = __builtin_amdgcn_mfma_f32_32x32x16_bf16(af, bf, c[nt], 0, 0, 0);
            }
        }
        const float* bias = mat ? bk : bq;
        float sc = mat ? 1.0f : QSCALE;
        ushort* Out = mat ? Kh : Qh;
        #pragma unroll
        for (int nt = 0; nt < 4; ++nt) {
            int dout = ng * 128 + nt * 32 + l31;
            int head = dout >> 6, d63 = dout & 63;
            float bb = bias[dout];
            size_t obase = ((size_t)(b * 4 + head) * TN + mtt * 32) * 64 + d63;
            #pragma unroll
            for (int u = 0; u < 16; ++u) {
                int trow = (u & 3) + 8 * (u >> 2) + 4 * h;
                Out[obase + (size_t)trow * 64] = f2b((c[nt][u] + bb) * sc);
            }
        }
    } else {
        int mtv = p & 7, tg = p >> 3;       // dout tile (8), t group (24)
        const ushort* arow = &Wm[(size_t)(mtv * 32 + l31) * 64];
        #pragma unroll
        for (int kc = 0; kc < 4; ++kc) {
            bf16x8 af = ld8(arow + kc * 16 + 8 * h);
            #pragma unroll
            for (int nt = 0; nt < 4; ++nt) {
                bf16x8 bf = ld8(&Xb[(size_t)(tg * 128 + nt * 32 + l31) * 64 + kc * 16 + 8 * h]);
                c[nt] = __builtin_amdgcn_mfma_f32_32x32x16_bf16(af, bf, c[nt], 0, 0, 0);
            }
        }
        int head = mtv >> 1;
        int sl = (l31 & 19) | ((l31 & 4) << 1) | ((l31 & 8) >> 1);  // swap bits 2<->3
        #pragma unroll
        for (int nt = 0; nt < 4; ++nt) {
            size_t tslot = (size_t)(tg * 128 + nt * 32 + sl);
            #pragma unroll
            for (int u = 0; u < 16; ++u) {
                int dout = mtv * 32 + (u & 3) + 8 * (u >> 2) + 4 * h;
                int d63 = dout & 63;
                Vt[((size_t)(b * 4 + head) * 64 + d63) * TN + tslot] =
                    f2b(c[nt][u] + bv[dout]);
            }
        }
    }
}

// ---- kernel 5: flash attention, BK=128, P in registers (r5 version, verbatim:
// passed full harness validation twice). 256 threads, 4 waves x 32 q, split-K x2.
__global__ __launch_bounds__(256, 3) void k_attn(
        const ushort* __restrict__ Qg, const ushort* __restrict__ Kg,
        const ushort* __restrict__ Vtg,
        float* __restrict__ OP0, float* __restrict__ OP1,
        float* __restrict__ Sml) {
    __shared__ __align__(16) ushort Ks[128 * 64];    // keys x d
    __shared__ __align__(16) ushort Vts[64 * 128];   // d x keys
    int bh = blockIdx.x / 48;
    int rem = blockIdx.x - bh * 48;
    int qt = rem >> 1, ks = rem & 1;
    int b = bh >> 2, hh = bh & 3;
    int tid = threadIdx.x, wave = tid >> 6, lane = tid & 63;
    int l31 = lane & 31, h = lane >> 5;
    const ushort* Kb = Kg + (size_t)bh * TN * DH;
    const ushort* Vtb = Vtg + (size_t)bh * DH * TN;
    int q0 = qt * 128 + wave * 32;
    const ushort* Qb = Qg + ((size_t)bh * TN + q0 + l31) * DH;
    bf16x8 qf[4];
    #pragma unroll
    for (int kc = 0; kc < 4; ++kc) qf[kc] = ld8(&Qb[kc * 16 + 8 * h]);

    // staging addresses (thread-fixed)
    int krow0 = tid >> 3, kcc = tid & 7;
    int vrow0 = tid >> 4, vch = tid & 15;
    int kt0 = ks * 1536;
    const ushort* KbL = Kb + (size_t)(kt0 + krow0) * 64 + kcc * 8;
    const ushort* VtL = Vtb + (size_t)vrow0 * TN + kt0 + vch * 8;

    f32x16 o0, o1;
    #pragma unroll
    for (int q = 0; q < 16; ++q) { o0[q] = 0.f; o1[q] = 0.f; }
    float lrun = 0.f;

    int fq0 = (l31 ^ (l31 >> 3)) & 7;
    int fq1 = ((32 + l31) ^ ((32 + l31) >> 3)) & 7;

    #pragma unroll 1
    for (int it = 0; it < 12; ++it) {
        __syncthreads();
        #pragma unroll
        for (int i = 0; i < 4; ++i) {
            int kr = krow0 + 32 * i;
            int fk = (kr ^ (kr >> 3)) & 7;
            *(uint4*)&Ks[kr * 64 + ((kcc ^ fk) << 3)] =
                *(const uint4*)(KbL + (size_t)(32 * i) * 64);
            int vr = vrow0 + 16 * i;
            int fv = (vr ^ (vr >> 3)) & 7;
            *(uint4*)&Vts[vr * 128 + (((vch & 8) | ((vch & 7) ^ fv)) << 3)] =
                *(const uint4*)(VtL + (size_t)(16 * i) * TN);
        }
        KbL += 128 * 64;
        VtL += 128;
        __syncthreads();

        uint pkA[32];
        float psum = 0.f;
        #pragma unroll
        for (int hf = 0; hf < 2; ++hf) {
            f32x16 s0, s1;
            #pragma unroll
            for (int q = 0; q < 16; ++q) { s0[q] = 0.f; s1[q] = 0.f; }
            int r0 = hf * 64 + l31, r1 = r0 + 32;
            // (hf*64)>>3 is a multiple of 8 -> f same as fq0/fq1
            #pragma unroll
            for (int kc = 0; kc < 4; ++kc) {
                int ch = 2 * kc + h;
                bf16x8 k0 = ld8(&Ks[r0 * 64 + ((ch ^ fq0) << 3)]);
                bf16x8 k1 = ld8(&Ks[r1 * 64 + ((ch ^ fq1) << 3)]);
                s0 = __builtin_amdgcn_mfma_f32_32x32x16_bf16(k0, qf[kc], s0, 0, 0, 0);
                s1 = __builtin_amdgcn_mfma_f32_32x32x16_bf16(k1, qf[kc], s1, 0, 0, 0);
            }
            #pragma unroll
            for (int u = 0; u < 8; ++u) {
                float pa = exp2f(s0[2 * u]), pb = exp2f(s0[2 * u + 1]);
                psum += pa + pb;
                pkA[hf * 16 + u] = cvtpk(pa, pb);
            }
            #pragma unroll
            for (int u = 0; u < 8; ++u) {
                float pa = exp2f(s1[2 * u]), pb = exp2f(s1[2 * u + 1]);
                psum += pa + pb;
                pkA[hf * 16 + 8 + u] = cvtpk(pa, pb);
            }
        }
        psum += __shfl_xor(psum, 32);
        lrun += psum;

        // PV: A = P (regs), B = V^T; chunks of 16 keys
        #pragma unroll
        for (int kc2 = 0; kc2 < 8; ++kc2) {
            U4B8 pf;
            pf.u[0] = pkA[4 * kc2];     pf.u[1] = pkA[4 * kc2 + 1];
            pf.u[2] = pkA[4 * kc2 + 2]; pf.u[3] = pkA[4 * kc2 + 3];
            int ch = 2 * kc2 + h;       // 0..15
            bf16x8 v0f = ld8(&Vts[l31 * 128 + (((ch & 8) | ((ch & 7) ^ fq0)) << 3)]);
            bf16x8 v1f = ld8(&Vts[(32 + l31) * 128 + (((ch & 8) | ((ch & 7) ^ fq1)) << 3)]);
            o0 = __builtin_amdgcn_mfma_f32_32x32x16_bf16(pf.v, v0f, o0, 0, 0, 0);
            o1 = __builtin_amdgcn_mfma_f32_32x32x16_bf16(pf.v, v1f, o1, 0, 0, 0);
        }
    }

    // epilogue: raw partial O (fp32) + per-row l
    float* OP = ks ? OP1 : OP0;
    #pragma unroll
    for (int q = 0; q < 16; ++q) {
        int qrow = (q & 3) + 8 * (q >> 2) + 4 * h;
        int t = q0 + qrow;
        size_t base = ((size_t)b * TN + t) * Dd + hh * 64;
        OP[base + l31] = o0[q];
        OP[base + 32 + l31] = o1[q];
    }
    if (h == 0)
        Sml[(size_t)ks * 49152 + (size_t)bh * TN + q0 + l31] = lrun;
}

// ---- kernel 6: output projection, LDS-staged, split-bf16 MFMA, fused combine ----
__global__ __launch_bounds__(256) void k_out(
        const float* __restrict__ OP0, const float* __restrict__ OP1,
        const float* __restrict__ Sml, const float* __restrict__ Wo,
        const float* __restrict__ bo, float* __restrict__ out) {
    __shared__ __align__(16) ushort Mhi[64 * 16];
    __shared__ __align__(16) ushort Mlo[64 * 16];
    __shared__ float invsh[64 * 4];
    int nd4 = blockIdx.x;              // 64-dout group (4)
    int R0 = blockIdx.y * 64;          // 64-token group (192)
    int b = R0 / TN;
    int tloc0 = R0 - b * TN;
    int tid = threadIdx.x, wave = tid >> 6, lane = tid & 63;
    int l31 = lane & 31, h = lane >> 5;
    int wt = wave & 1, wd = wave >> 1;
    {
        int hd = tid >> 6, t = tid & 63;
        size_t o = (size_t)(b * 4 + hd) * TN + tloc0 + t;
        invsh[t * 4 + hd] = 1.f / (Sml[o] + Sml[49152 + o]);
    }
    int dout = nd4 * 64 + wd * 32 + l31;
    float bb = bo[dout];
    const float* wrow = &Wo[(size_t)dout * 256];
    int st_t = tid >> 2, st_c = tid & 3;
    size_t st_base = ((size_t)(b * TN + tloc0 + st_t)) * 256 + st_c * 4;
    f32x16 acc;
    #pragma unroll
    for (int q = 0; q < 16; ++q) acc[q] = 0.f;
    #pragma unroll 1
    for (int st = 0; st < 16; ++st) {
        __syncthreads();
        int hd = st >> 2;
        {
            size_t ob = st_base + st * 16;
            float4 x = *(const float4*)&OP0[ob];
            float4 y = *(const float4*)&OP1[ob];
            float s = invsh[st_t * 4 + hd];
            float m0 = (x.x + y.x) * s, m1 = (x.y + y.y) * s;
            float m2 = (x.z + y.z) * s, m3 = (x.w + y.w) * s;
            uint2 wh = { trunc_pk(m0, m1), trunc_pk(m2, m3) };
            uint2 wl = { trunc_pk(m0 - hi_f(m0), m1 - hi_f(m1)),
                         trunc_pk(m2 - hi_f(m2), m3 - hi_f(m3)) };
            *(uint2*)&Mhi[st_t * 16 + st_c * 4] = wh;
            *(uint2*)&Mlo[st_t * 16 + st_c * 4] = wl;
        }
        __syncthreads();
        int din0 = st * 16 + 8 * h;
        float4 w0 = *(const float4*)&wrow[din0];
        float4 w1 = *(const float4*)&wrow[din0 + 4];
        U4B8 wh, wl;
        wh.u[0] = trunc_pk(w0.x, w0.y); wh.u[1] = trunc_pk(w0.z, w0.w);
        wh.u[2] = trunc_pk(w1.x, w1.y); wh.u[3] = trunc_pk(w1.z, w1.w);
        wl.u[0] = trunc_pk(w0.x - hi_f(w0.x), w0.y - hi_f(w0.y));
        wl.u[1] = trunc_pk(w0.z - hi_f(w0.z), w0.w - hi_f(w0.w));
        wl.u[2] = trunc_pk(w1.x - hi_f(w1.x), w1.y - hi_f(w1.y));
        wl.u[3] = trunc_pk(w1.z - hi_f(w1.z), w1.w - hi_f(w1.w));
        int trow = wt * 32 + l31;
        bf16x8 ah = *(const bf16x8*)&Mhi[trow * 16 + 8 * h];
        bf16x8 al = *(const bf16x8*)&Mlo[trow * 16 + 8 * h];
        acc = __builtin_amdgcn_mfma_f32_32x32x16_bf16(ah, wh.v, acc, 0, 0, 0);
        acc = __builtin_amdgcn_mfma_f32_32x32x16_bf16(al, wh.v, acc, 0, 0, 0);
        acc = __builtin_amdgcn_mfma_f32_32x32x16_bf16(ah, wl.v, acc, 0, 0, 0);
    }
    #pragma unroll
    for (int u = 0; u < 16; ++u) {
        int tloc = tloc0 + wt * 32 + (u & 3) + 8 * (u >> 2) + 4 * h;
        int chunk = tloc >> 10, tt = tloc & 1023;
        out[(size_t)chunk * (Bsz * Nn * Dd) + ((size_t)(b * Nn + tt)) * Dd + dout] =
            acc[u] + bb;
    }
}

extern "C" void kernel_launch(void* const* d_in, const int* in_sizes, int n_in,
                              void* d_out, int out_size, void* d_ws, size_t ws_size,
                              hipStream_t stream) {
    const float* F0 = (const float*)d_in[0];
    const float* F1 = (const float*)d_in[1];
    const float* F2 = (const float*)d_in[2];
    const float* Wq = (const float*)d_in[3];
    const float* bq = (const float*)d_in[4];
    const float* Wk = (const float*)d_in[5];
    const float* bk = (const float*)d_in[6];
    const float* Wv = (const float*)d_in[7];
    const float* bv = (const float*)d_in[8];
    const float* Wo = (const float*)d_in[9];
    const float* bo = (const float*)d_in[10];
    float* ws = (float*)d_ws;
    float* out = (float*)d_out;

    int* idxp = (int*)(ws + IDX_OFF);
    uint* Xcb = (uint*)(ws + XCB_OFF);
    uint* Wct = (uint*)(ws + WCT_OFF);
    ushort* Qb16 = (ushort*)(ws + QB_OFF);
    ushort* Kb16 = (ushort*)(ws + KB_OFF);
    ushort* Vt16 = (ushort*)(ws + VT_OFF);
    float* OP0 = ws + OP0_OFF;
    float* OP1 = ws + OP1_OFF;
    float* Sml = ws + SML_OFF;

    k_sal<<<384, 256, 0, stream>>>(F0, F1, F2, ws + SALP_OFF);
    k_topk<<<Bsz, 256, 0, stream>>>(ws + SALP_OFF, idxp);
    k_gather<<<768, 256, 0, stream>>>(F0, F1, F2, Wq, Wk, Wv, idxp, Xcb, Wct);
    k_qkv<<<576, 256, 0, stream>>>((const ushort*)Xcb, (const ushort*)Wct,
                                   bq, bk, bv, Qb16, Kb16, Vt16);
    k_attn<<<768, 256, 0, stream>>>(Qb16, Kb16, Vt16, OP0, OP1, Sml);
    k_out<<<dim3(4, 192), 256, 0, stream>>>(OP0, OP1, Sml, Wo, bo, out);
}

// Round 9
// 187.820 us; speedup vs baseline: 1.4834x; 1.0337x over previous
//
#include <hip/hip_runtime.h>
#include <math.h>

typedef __attribute__((ext_vector_type(8))) short bf16x8;
typedef __attribute__((ext_vector_type(16))) float f32x16;

#define Bsz 4
#define Nn 1024
#define TN 3072
#define Dd 256
#define Hh 4
#define DH 64
#define TAUc 1e-3f
#define QSCALE 0.1803368801111f   // log2(e)/8 : softmax done in exp2 domain

// workspace layout (float offsets)
#define SALP_OFF 0           // 98304 (4 b x 96 slabs x 256 d partial sums)
#define IDX_OFF  98304       // 256 ints
#define XCB_OFF  98560       // bf16 (4,3072,64) = 393216 floats
#define WCT_OFF  491776      // bf16 (4,3,256,64) = 98304 floats
#define QB_OFF   590080      // bf16 (16,3072,64) linear
#define KB_OFF   2162944     // bf16 (16 bh,24 tiles,128 row,8 chunk,8) swizzled tiles
#define VT_OFF   3735808     // bf16 (16 bh,24 tiles,64 row,16 chunk,8) swizzled tiles
#define OP0_OFF  5308672     // fp32 (4,3072,256) split-K partial 0
#define OP1_OFF  8454400     // fp32 partial 1
#define SML_OFF  11600128    // float [2][16][3072] row sums l

__device__ __forceinline__ ushort f2b(float f) {
    uint u = __float_as_uint(f);
    u += 0x7fffu + ((u >> 16) & 1u);
    return (ushort)(u >> 16);
}
__device__ __forceinline__ uint pk2(float a, float b) {   // RNE pack (software)
    return (uint)f2b(a) | ((uint)f2b(b) << 16);
}
__device__ __forceinline__ uint trunc_pk(float a, float b) {
    return (__float_as_uint(a) >> 16) | (__float_as_uint(b) & 0xFFFF0000u);
}
__device__ __forceinline__ float hi_f(float a) {
    return __uint_as_float(__float_as_uint(a) & 0xFFFF0000u);
}
__device__ __forceinline__ uint cvtpk(float a, float b) {  // HW RNE pack
    uint r;
    asm("v_cvt_pk_bf16_f32 %0, %1, %2" : "=v"(r) : "v"(a), "v"(b));
    return r;
}
// async global->LDS DMA, 16B per lane (lane-linear LDS destination)
__device__ __forceinline__ void gld16(const ushort* g, ushort* l) {
    __builtin_amdgcn_global_load_lds(
        (const __attribute__((address_space(1))) uint*)g,
        (__attribute__((address_space(3))) uint*)l, 16, 0, 0);
}
union U4B8 { uint u[4]; bf16x8 v; };
__device__ __forceinline__ bf16x8 ld8(const ushort* p) { return *(const bf16x8*)p; }

// ---- kernel 1: per-channel saliency partial sums ----
__global__ __launch_bounds__(256) void k_sal(
        const float* __restrict__ F0, const float* __restrict__ F1,
        const float* __restrict__ F2, float* __restrict__ salp) {
    int b = blockIdx.x / 96;
    int slab = blockIdx.x - b * 96;
    int t0 = slab * 32;
    int seg = t0 >> 10, tt0 = t0 & 1023;
    const float* F = (seg == 0) ? F0 : (seg == 1 ? F1 : F2);
    const float* base = &F[(size_t)((b << 10) + tt0) * Dd + threadIdx.x];
    float acc = 0.f;
    #pragma unroll 4
    for (int r = 0; r < 32; ++r) {
        float x = base[(size_t)r * Dd];
        acc += fmaxf(fabsf(x) - TAUc, 0.f);
    }
    salp[blockIdx.x * 256 + threadIdx.x] = acc;
}

// ---- kernel 2: reduce partials + top-64 selection (bitonic sort 256) ----
__global__ void k_topk(const float* __restrict__ salp, int* __restrict__ idx) {
    __shared__ float v[256];
    __shared__ int cnt;
    int b = blockIdx.x, tid = threadIdx.x;
    float myval = 0.f;
    const float* p = &salp[(size_t)b * 96 * 256 + tid];
    #pragma unroll 4
    for (int s = 0; s < 96; ++s) myval += p[s * 256];
    v[tid] = myval;
    if (tid == 0) cnt = 0;
    __syncthreads();
    for (int k = 2; k <= 256; k <<= 1)
        for (int j = k >> 1; j > 0; j >>= 1) {
            int ixj = tid ^ j;
            if (ixj > tid) {
                float a = v[tid], c = v[ixj];
                bool up = ((tid & k) == 0);
                if ((a > c) == up) { v[tid] = c; v[ixj] = a; }
            }
            __syncthreads();
        }
    float thr = v[192];
    if (myval >= thr) {
        int p2 = atomicAdd(&cnt, 1);
        if (p2 < 64) idx[b * 64 + p2] = tid;
    }
}

// ---- kernel 3: merged gathers (blocks 0..383: X; 384..767: W columns) ----
__global__ __launch_bounds__(256) void k_gather(
        const float* __restrict__ F0, const float* __restrict__ F1,
        const float* __restrict__ F2,
        const float* __restrict__ Wq, const float* __restrict__ Wk,
        const float* __restrict__ Wv, const int* __restrict__ idx,
        uint* __restrict__ Xcb, uint* __restrict__ Wct) {
    __shared__ float xs[32 * 260];
    __shared__ int ids[64];
    int tid = threadIdx.x;
    if (blockIdx.x < 384) {
        int b = blockIdx.x / 96;
        int t0 = (blockIdx.x - b * 96) * 32;
        if (tid < 64) ids[tid] = idx[b * 64 + tid];
        int seg = t0 >> 10, tt0 = t0 & 1023;
        const float* F = (seg == 0) ? F0 : (seg == 1 ? F1 : F2);
        const float* base = &F[(size_t)((b << 10) + tt0) * Dd];
        #pragma unroll
        for (int i = 0; i < 8; ++i) {
            int i0 = tid + i * 256;
            int r = i0 >> 6, c4 = (i0 & 63) << 2;
            float4 x = *(const float4*)&base[(size_t)r * Dd + c4];
            x.x = copysignf(fmaxf(fabsf(x.x) - TAUc, 0.f), x.x);
            x.y = copysignf(fmaxf(fabsf(x.y) - TAUc, 0.f), x.y);
            x.z = copysignf(fmaxf(fabsf(x.z) - TAUc, 0.f), x.z);
            x.w = copysignf(fmaxf(fabsf(x.w) - TAUc, 0.f), x.w);
            *(float4*)&xs[r * 260 + c4] = x;
        }
        __syncthreads();
        #pragma unroll
        for (int i = 0; i < 4; ++i) {
            int i0 = tid + i * 256;
            int r = i0 >> 5, jp = i0 & 31;
            float x0 = xs[r * 260 + ids[2 * jp]];
            float x1 = xs[r * 260 + ids[2 * jp + 1]];
            Xcb[(size_t)(b * TN + t0 + r) * 32 + jp] = pk2(x0, x1);
        }
    } else {
        int gid = (blockIdx.x - 384) * 256 + tid;   // 98304
        int b = gid / 24576;
        if (tid < 64) ids[tid] = idx[b * 64 + tid];
        __syncthreads();
        int rem = gid - b * 24576;
        int mat = rem / 8192;
        int rem2 = rem - mat * 8192;
        int dout = rem2 >> 5, jp = rem2 & 31;
        const float* Wm = (mat == 0) ? Wq : (mat == 1 ? Wk : Wv);
        float w0 = Wm[(size_t)dout * 256 + ids[2 * jp]];
        float w1 = Wm[(size_t)dout * 256 + ids[2 * jp + 1]];
        Wct[((size_t)(b * 3 + mat) * 256 + dout) * 32 + jp] = pk2(w0, w1);
    }
}

// ---- kernel 4: QKV projection, 32x32x16 MFMA, LDS-free ----
// Q: linear (b,h,t,d), pre-scaled. K/V: written directly in the SWIZZLED TILE
// layout k_attn's LDS image uses, so k_attn can DMA tiles with global_load_lds.
__global__ __launch_bounds__(256) void k_qkv(
        const ushort* __restrict__ Xcb, const ushort* __restrict__ Wct,
        const float* __restrict__ bq, const float* __restrict__ bk,
        const float* __restrict__ bv,
        ushort* __restrict__ Qh, ushort* __restrict__ Kh, ushort* __restrict__ Vt) {
    int wave = threadIdx.x >> 6, lane = threadIdx.x & 63;
    int l31 = lane & 31, h = lane >> 5;
    int W = blockIdx.x * 4 + wave;          // 2304 wave-tasks
    int b = W / 576;
    int r = W - b * 576;
    int mat = r / 192;
    int p = r - mat * 192;
    const ushort* Xb = Xcb + (size_t)b * TN * 64;
    const ushort* Wm = Wct + (size_t)(b * 3 + mat) * 256 * 64;
    f32x16 c[4];
    #pragma unroll
    for (int nt = 0; nt < 4; ++nt)
        #pragma unroll
        for (int q = 0; q < 16; ++q) c[nt][q] = 0.f;
    if (mat < 2) {
        int mtt = p % 96, ng = p / 96;      // t tile, dout half
        const ushort* arow = &Xb[(size_t)(mtt * 32 + l31) * 64];
        #pragma unroll
        for (int kc = 0; kc < 4; ++kc) {
            bf16x8 af = ld8(arow + kc * 16 + 8 * h);
            #pragma unroll
            for (int nt = 0; nt < 4; ++nt) {
                bf16x8 bf = ld8(&Wm[(size_t)(ng * 128 + nt * 32 + l31) * 64 + kc * 16 + 8 * h]);
                c[nt] = __builtin_amdgcn_mfma_f32_32x32x16_bf16(af, bf, c[nt], 0, 0, 0);
            }
        }
        if (mat == 0) {
            // Q: linear coalesced stores, pre-scaled
            #pragma unroll
            for (int nt = 0; nt < 4; ++nt) {
                int dout = ng * 128 + nt * 32 + l31;
                int head = dout >> 6, d63 = dout & 63;
                float bb = bq[dout];
                size_t obase = ((size_t)(b * 4 + head) * TN + mtt * 32) * 64 + d63;
                #pragma unroll
                for (int u = 0; u < 16; ++u) {
                    int trow = (u & 3) + 8 * (u >> 2) + 4 * h;
                    Qh[obase + (size_t)trow * 64] = f2b((c[nt][u] + bb) * QSCALE);
                }
            }
        } else {
            // K: swizzled tile layout: [bh][tile=t>>7][row=t&127][chunk=(d>>3)^fk][d&7]
            #pragma unroll
            for (int nt = 0; nt < 4; ++nt) {
                int dout = ng * 128 + nt * 32 + l31;
                int head = dout >> 6, d63 = dout & 63;
                float bb = bk[dout];
                size_t base = (size_t)(b * 4 + head) * 196608;
                #pragma unroll
                for (int u = 0; u < 16; ++u) {
                    int trow = (u & 3) + 8 * (u >> 2) + 4 * h;
                    int t = mtt * 32 + trow;
                    int row = t & 127, tile = t >> 7;
                    int fk = (row ^ (row >> 3)) & 7;
                    Kh[base + (size_t)tile * 8192 + row * 64 +
                       (((d63 >> 3) ^ fk) << 3) + (d63 & 7)] = f2b(c[nt][u] + bb);
                }
            }
        }
    } else {
        int mtv = p & 7, tg = p >> 3;       // dout tile (8), t group (24 = key tile)
        const ushort* arow = &Wm[(size_t)(mtv * 32 + l31) * 64];
        #pragma unroll
        for (int kc = 0; kc < 4; ++kc) {
            bf16x8 af = ld8(arow + kc * 16 + 8 * h);
            #pragma unroll
            for (int nt = 0; nt < 4; ++nt) {
                bf16x8 bf = ld8(&Xb[(size_t)(tg * 128 + nt * 32 + l31) * 64 + kc * 16 + 8 * h]);
                c[nt] = __builtin_amdgcn_mfma_f32_32x32x16_bf16(af, bf, c[nt], 0, 0, 0);
            }
        }
        int head = mtv >> 1;
        int sl = (l31 & 19) | ((l31 & 4) << 1) | ((l31 & 8) >> 1);  // swap bits 2<->3
        size_t vbase = (size_t)(b * 4 + head) * 196608 + (size_t)tg * 8192;
        // V: swizzled tile: [bh][tile=tg][row=d&63][chunk'=(c&8)|((c&7)^fv)][key&7]
        #pragma unroll
        for (int nt = 0; nt < 4; ++nt) {
            int cc = (nt * 32 + sl) >> 3;   // key chunk within tile (0..15)
            int elem = sl & 7;
            #pragma unroll
            for (int u = 0; u < 16; ++u) {
                int dout = mtv * 32 + (u & 3) + 8 * (u >> 2) + 4 * h;
                int row = dout & 63;
                int fv = (row ^ (row >> 3)) & 7;
                int ch = (cc & 8) | ((cc & 7) ^ fv);
                Vt[vbase + row * 128 + ch * 8 + elem] = f2b(c[nt][u] + bv[dout]);
            }
        }
    }
}

// ---- kernel 5: flash attention (r8/r5-verified compute), staging via
// global_load_lds DMA of pre-swizzled 16KB K/V tiles. LDS image, fragment
// reads, softmax, PV register-P, and epilogue are byte-identical to r8.
__global__ __launch_bounds__(256, 3) void k_attn(
        const ushort* __restrict__ Qg, const ushort* __restrict__ Kg,
        const ushort* __restrict__ Vtg,
        float* __restrict__ OP0, float* __restrict__ OP1,
        float* __restrict__ Sml) {
    __shared__ __align__(16) ushort Ks[128 * 64];    // keys x d (swizzled image)
    __shared__ __align__(16) ushort Vts[64 * 128];   // d x keys (swizzled image)
    int bh = blockIdx.x / 48;
    int rem = blockIdx.x - bh * 48;
    int qt = rem >> 1, ks = rem & 1;
    int b = bh >> 2, hh = bh & 3;
    int tid = threadIdx.x, wave = tid >> 6, lane = tid & 63;
    int l31 = lane & 31, h = lane >> 5;
    int q0 = qt * 128 + wave * 32;
    const ushort* Qb = Qg + ((size_t)bh * TN + q0 + l31) * DH;
    bf16x8 qf[4];
    #pragma unroll
    for (int kc = 0; kc < 4; ++kc) qf[kc] = ld8(&Qb[kc * 16 + 8 * h]);

    const ushort* Kt = Kg + (size_t)bh * 196608 + (size_t)(ks * 12) * 8192 + tid * 8;
    const ushort* Vtt = Vtg + (size_t)bh * 196608 + (size_t)(ks * 12) * 8192 + tid * 8;

    f32x16 o0, o1;
    #pragma unroll
    for (int q = 0; q < 16; ++q) { o0[q] = 0.f; o1[q] = 0.f; }
    float lrun = 0.f;

    int fq0 = (l31 ^ (l31 >> 3)) & 7;
    int fq1 = ((32 + l31) ^ ((32 + l31) >> 3)) & 7;

    #pragma unroll 1
    for (int it = 0; it < 12; ++it) {
        __syncthreads();
        #pragma unroll
        for (int i = 0; i < 4; ++i) {
            gld16(Kt + i * 2048, &Ks[(tid + i * 256) * 8]);
            gld16(Vtt + i * 2048, &Vts[(tid + i * 256) * 8]);
        }
        Kt += 8192; Vtt += 8192;
        __syncthreads();

        uint pkA[32];
        float psum = 0.f;
        #pragma unroll
        for (int hf = 0; hf < 2; ++hf) {
            f32x16 s0, s1;
            #pragma unroll
            for (int q = 0; q < 16; ++q) { s0[q] = 0.f; s1[q] = 0.f; }
            int r0 = hf * 64 + l31, r1 = r0 + 32;
            #pragma unroll
            for (int kc = 0; kc < 4; ++kc) {
                int ch = 2 * kc + h;
                bf16x8 k0 = ld8(&Ks[r0 * 64 + ((ch ^ fq0) << 3)]);
                bf16x8 k1 = ld8(&Ks[r1 * 64 + ((ch ^ fq1) << 3)]);
                s0 = __builtin_amdgcn_mfma_f32_32x32x16_bf16(k0, qf[kc], s0, 0, 0, 0);
                s1 = __builtin_amdgcn_mfma_f32_32x32x16_bf16(k1, qf[kc], s1, 0, 0, 0);
            }
            #pragma unroll
            for (int u = 0; u < 8; ++u) {
                float pa = exp2f(s0[2 * u]), pb = exp2f(s0[2 * u + 1]);
                psum += pa + pb;
                pkA[hf * 16 + u] = cvtpk(pa, pb);
            }
            #pragma unroll
            for (int u = 0; u < 8; ++u) {
                float pa = exp2f(s1[2 * u]), pb = exp2f(s1[2 * u + 1]);
                psum += pa + pb;
                pkA[hf * 16 + 8 + u] = cvtpk(pa, pb);
            }
        }
        psum += __shfl_xor(psum, 32);
        lrun += psum;

        #pragma unroll
        for (int kc2 = 0; kc2 < 8; ++kc2) {
            U4B8 pf;
            pf.u[0] = pkA[4 * kc2];     pf.u[1] = pkA[4 * kc2 + 1];
            pf.u[2] = pkA[4 * kc2 + 2]; pf.u[3] = pkA[4 * kc2 + 3];
            int ch = 2 * kc2 + h;       // 0..15
            bf16x8 v0f = ld8(&Vts[l31 * 128 + (((ch & 8) | ((ch & 7) ^ fq0)) << 3)]);
            bf16x8 v1f = ld8(&Vts[(32 + l31) * 128 + (((ch & 8) | ((ch & 7) ^ fq1)) << 3)]);
            o0 = __builtin_amdgcn_mfma_f32_32x32x16_bf16(pf.v, v0f, o0, 0, 0, 0);
            o1 = __builtin_amdgcn_mfma_f32_32x32x16_bf16(pf.v, v1f, o1, 0, 0, 0);
        }
    }

    float* OP = ks ? OP1 : OP0;
    #pragma unroll
    for (int q = 0; q < 16; ++q) {
        int qrow = (q & 3) + 8 * (q >> 2) + 4 * h;
        int t = q0 + qrow;
        size_t base = ((size_t)b * TN + t) * Dd + hh * 64;
        OP[base + l31] = o0[q];
        OP[base + 32 + l31] = o1[q];
    }
    if (h == 0)
        Sml[(size_t)ks * 49152 + (size_t)bh * TN + q0 + l31] = lrun;
}

// ---- kernel 6: output projection v2 — double-buffered LDS, 8 stages x 32 din,
// XOR-swizzled M tile, split-bf16 MFMA (identical math to r8), fused combine ----
__global__ __launch_bounds__(256) void k_out(
        const float* __restrict__ OP0, const float* __restrict__ OP1,
        const float* __restrict__ Sml, const float* __restrict__ Wo,
        const float* __restrict__ bo, float* __restrict__ out) {
    __shared__ __align__(16) ushort Ms[2][64][64];   // [buf][t][8 chunks: hi 0-3, lo 4-7]
    __shared__ float invsh[64 * 4];
    int nd4 = blockIdx.x;              // 64-dout group (4)
    int R0 = blockIdx.y * 64;          // 64-token group (192)
    int b = R0 / TN;
    int tloc0 = R0 - b * TN;
    int tid = threadIdx.x, wave = tid >> 6, lane = tid & 63;
    int l31 = lane & 31, h = lane >> 5;
    int wt = wave & 1, wd = wave >> 1;
    {
        int hd = tid >> 6, t = tid & 63;
        size_t o = (size_t)(b * 4 + hd) * TN + tloc0 + t;
        invsh[t * 4 + hd] = 1.f / (Sml[o] + Sml[49152 + o]);
    }
    int dout = nd4 * 64 + wd * 32 + l31;
    float bb = bo[dout];
    const float* wrow = &Wo[(size_t)dout * 256];
    int st_t = tid >> 2, st_c = tid & 3;
    int fst = (st_t ^ (st_t >> 3)) & 7;
    size_t gbase = ((size_t)(b * TN + tloc0 + st_t)) * 256 + st_c * 8;
    int trow = wt * 32 + l31;
    int ftr = (trow ^ (trow >> 3)) & 7;
    f32x16 acc;
    #pragma unroll
    for (int q = 0; q < 16; ++q) acc[q] = 0.f;

    auto stage_load = [&](int st, int buf) {
        size_t ob = gbase + (size_t)st * 32;
        float4 x0 = *(const float4*)&OP0[ob];
        float4 x1 = *(const float4*)&OP0[ob + 4];
        float4 y0 = *(const float4*)&OP1[ob];
        float4 y1 = *(const float4*)&OP1[ob + 4];
        float s = invsh[st_t * 4 + (st >> 1)];
        float m0 = (x0.x + y0.x) * s, m1 = (x0.y + y0.y) * s;
        float m2 = (x0.z + y0.z) * s, m3 = (x0.w + y0.w) * s;
        float m4 = (x1.x + y1.x) * s, m5 = (x1.y + y1.y) * s;
        float m6 = (x1.z + y1.z) * s, m7 = (x1.w + y1.w) * s;
        uint4 hi = { trunc_pk(m0, m1), trunc_pk(m2, m3),
                     trunc_pk(m4, m5), trunc_pk(m6, m7) };
        uint4 lo = { trunc_pk(m0 - hi_f(m0), m1 - hi_f(m1)),
                     trunc_pk(m2 - hi_f(m2), m3 - hi_f(m3)),
                     trunc_pk(m4 - hi_f(m4), m5 - hi_f(m5)),
                     trunc_pk(m6 - hi_f(m6), m7 - hi_f(m7)) };
        *(uint4*)&Ms[buf][st_t][(st_c ^ fst) * 8] = hi;
        *(uint4*)&Ms[buf][st_t][((4 + st_c) ^ fst) * 8] = lo;
    };

    __syncthreads();            // invsh visible
    stage_load(0, 0);
    #pragma unroll 1
    for (int st = 0; st < 8; ++st) {
        __syncthreads();        // buf[st&1] visible; previous reads complete
        if (st < 7) stage_load(st + 1, (st + 1) & 1);
        int buf = st & 1;
        #pragma unroll
        for (int kc = 0; kc < 2; ++kc) {
            bf16x8 ah = *(const bf16x8*)&Ms[buf][trow][((2 * kc + h) ^ ftr) * 8];
            bf16x8 al = *(const bf16x8*)&Ms[buf][trow][((4 + 2 * kc + h) ^ ftr) * 8];
            int din0 = st * 32 + kc * 16 + 8 * h;
            float4 w0 = *(const float4*)&wrow[din0];
            float4 w1 = *(const float4*)&wrow[din0 + 4];
            U4B8 wh, wl;
            wh.u[0] = trunc_pk(w0.x, w0.y); wh.u[1] = trunc_pk(w0.z, w0.w);
            wh.u[2] = trunc_pk(w1.x, w1.y); wh.u[3] = trunc_pk(w1.z, w1.w);
            wl.u[0] = trunc_pk(w0.x - hi_f(w0.x), w0.y - hi_f(w0.y));
            wl.u[1] = trunc_pk(w0.z - hi_f(w0.z), w0.w - hi_f(w0.w));
            wl.u[2] = trunc_pk(w1.x - hi_f(w1.x), w1.y - hi_f(w1.y));
            wl.u[3] = trunc_pk(w1.z - hi_f(w1.z), w1.w - hi_f(w1.w));
            acc = __builtin_amdgcn_mfma_f32_32x32x16_bf16(ah, wh.v, acc, 0, 0, 0);
            acc = __builtin_amdgcn_mfma_f32_32x32x16_bf16(al, wh.v, acc, 0, 0, 0);
            acc = __builtin_amdgcn_mfma_f32_32x32x16_bf16(ah, wl.v, acc, 0, 0, 0);
        }
    }
    #pragma unroll
    for (int u = 0; u < 16; ++u) {
        int tloc = tloc0 + wt * 32 + (u & 3) + 8 * (u >> 2) + 4 * h;
        int chunk = tloc >> 10, tt = tloc & 1023;
        out[(size_t)chunk * (Bsz * Nn * Dd) + ((size_t)(b * Nn + tt)) * Dd + dout] =
            acc[u] + bb;
    }
}

extern "C" void kernel_launch(void* const* d_in, const int* in_sizes, int n_in,
                              void* d_out, int out_size, void* d_ws, size_t ws_size,
                              hipStream_t stream) {
    const float* F0 = (const float*)d_in[0];
    const float* F1 = (const float*)d_in[1];
    const float* F2 = (const float*)d_in[2];
    const float* Wq = (const float*)d_in[3];
    const float* bq = (const float*)d_in[4];
    const float* Wk = (const float*)d_in[5];
    const float* bk = (const float*)d_in[6];
    const float* Wv = (const float*)d_in[7];
    const float* bv = (const float*)d_in[8];
    const float* Wo = (const float*)d_in[9];
    const float* bo = (const float*)d_in[10];
    float* ws = (float*)d_ws;
    float* out = (float*)d_out;

    int* idxp = (int*)(ws + IDX_OFF);
    uint* Xcb = (uint*)(ws + XCB_OFF);
    uint* Wct = (uint*)(ws + WCT_OFF);
    ushort* Qb16 = (ushort*)(ws + QB_OFF);
    ushort* Kb16 = (ushort*)(ws + KB_OFF);
    ushort* Vt16 = (ushort*)(ws + VT_OFF);
    float* OP0 = ws + OP0_OFF;
    float* OP1 = ws + OP1_OFF;
    float* Sml = ws + SML_OFF;

    k_sal<<<384, 256, 0, stream>>>(F0, F1, F2, ws + SALP_OFF);
    k_topk<<<Bsz, 256, 0, stream>>>(ws + SALP_OFF, idxp);
    k_gather<<<768, 256, 0, stream>>>(F0, F1, F2, Wq, Wk, Wv, idxp, Xcb, Wct);
    k_qkv<<<576, 256, 0, stream>>>((const ushort*)Xcb, (const ushort*)Wct,
                                   bq, bk, bv, Qb16, Kb16, Vt16);
    k_attn<<<768, 256, 0, stream>>>(Qb16, Kb16, Vt16, OP0, OP1, Sml);
    k_out<<<dim3(4, 192), 256, 0, stream>>>(OP0, OP1, Sml, Wo, bo, out);
}